// Round 7
// baseline (1308.133 us; speedup 1.0000x reference)
//
#include <hip/hip_runtime.h>
#include <math.h>

#define NTOT 8500

// ---------------------------------------------------------------------------
// Geometry: 4 scales concatenated along n: [6400 | 1600 | 400 | 100] = 8500.
// All boundaries divisible by 4 -> float4 loads never straddle scales.
//
// ROUND 7 RESTRUCTURE: conv1 is algebraically eliminated.
//   z-logits = X^T (W1^T mu) + (b1 . mu_k)          [tiny t,s + big GEMM on X]
//   mu'      = l2norm( W1 (X z) + b1 * colsum(z) )  [big GEMM on X + tiny W1@Y]
// Big-GEMM count drops 7 -> 7 (same sizes) but conv1 (270us) + xt write gone.
// ---------------------------------------------------------------------------
__device__ __forceinline__ size_t in_index(int gn, int bc, int* which) {
  if (gn < 6400) { *which = 0; return (size_t)bc * 6400 + gn; }
  if (gn < 8000) { *which = 1; return (size_t)bc * 1600 + (gn - 6400); }
  if (gn < 8400) { *which = 2; return (size_t)bc * 400  + (gn - 8000); }
  *which = 3;     return (size_t)bc * 100  + (gn - 8400);
}

// ---------------------------------------------------------------------------
// conv2: per batch GEMM out[o,n] = sum_c W[o,c]*xrec[c,n], epilogue BN +
// residual + relu, scattered writes into the 4 output scale segments.
// tile: 64 (o) x 128 (n), 256 threads, thread = 4x8, K-chunks of 32.
// ---------------------------------------------------------------------------
__global__ __launch_bounds__(256)
void conv2_kernel(const float* __restrict__ W,
                  const float* __restrict__ x0, const float* __restrict__ x1,
                  const float* __restrict__ x2, const float* __restrict__ x3,
                  const float* __restrict__ xrec,
                  const float* __restrict__ bn_g, const float* __restrict__ bn_b,
                  const float* __restrict__ bn_m, const float* __restrict__ bn_v,
                  float* __restrict__ out)
{
  __shared__ float As[32][68];    // [kk][o]
  __shared__ float Bs[32][132];   // [kk][n]
  const int t  = threadIdx.x;
  const int n0 = blockIdx.x * 128;
  const int m0 = blockIdx.y * 64;
  const int b  = blockIdx.z;
  const int tm = t & 15, tn = t >> 4;

  float acc[4][8];
#pragma unroll
  for (int i = 0; i < 4; ++i)
#pragma unroll
    for (int j = 0; j < 8; ++j) acc[i][j] = 0.f;

  for (int k0 = 0; k0 < 256; k0 += 32) {
#pragma unroll
    for (int it = 0; it < 2; ++it) {
      const int o_l = (t >> 3) + 32 * it;
      const int kk4 = (t & 7) * 4;
      float4 v = *(const float4*)(W + (size_t)(m0 + o_l) * 256 + k0 + kk4);
      As[kk4 + 0][o_l] = v.x; As[kk4 + 1][o_l] = v.y;
      As[kk4 + 2][o_l] = v.z; As[kk4 + 3][o_l] = v.w;
    }
#pragma unroll
    for (int it = 0; it < 4; ++it) {
      const int kk  = (t >> 5) + 8 * it;
      const int nn4 = (t & 31) * 4;
      const int gn  = n0 + nn4;
      float4 v = make_float4(0.f, 0.f, 0.f, 0.f);
      if (gn < NTOT)
        v = *(const float4*)(xrec + (size_t)(b * 256 + k0 + kk) * NTOT + gn);
      *(float4*)&Bs[kk][nn4] = v;
    }
    __syncthreads();
#pragma unroll
    for (int kk = 0; kk < 32; ++kk) {
      float4 a = *(const float4*)&As[kk][tm * 4];
      float4 p = *(const float4*)&Bs[kk][tn * 8];
      float4 q = *(const float4*)&Bs[kk][tn * 8 + 4];
      float av[4] = {a.x, a.y, a.z, a.w};
      float bv[8] = {p.x, p.y, p.z, p.w, q.x, q.y, q.z, q.w};
#pragma unroll
      for (int i = 0; i < 4; ++i)
#pragma unroll
        for (int j = 0; j < 8; ++j)
          acc[i][j] = fmaf(av[i], bv[j], acc[i][j]);
    }
    __syncthreads();
  }

#pragma unroll
  for (int i = 0; i < 4; ++i) {
    const int o = m0 + tm * 4 + i;
    float g   = bn_g[o];
    float isf = g / sqrtf(bn_v[o] + 1e-5f);
    float shf = bn_b[o] - bn_m[o] * isf;
#pragma unroll
    for (int jj = 0; jj < 8; jj += 4) {
      const int gn = n0 + tn * 8 + jj;
      if (gn >= NTOT) continue;
      float4 r = make_float4(acc[i][jj + 0], acc[i][jj + 1],
                             acc[i][jj + 2], acc[i][jj + 3]);
      int w_; size_t idx = in_index(gn, b * 256 + o, &w_);
      const float* src = (w_ == 0) ? x0 : (w_ == 1) ? x1 : (w_ == 2) ? x2 : x3;
      float4 rv = *(const float4*)(src + idx);
      size_t ob = (w_ == 0) ? 0ull : (w_ == 1) ? 26214400ull
                : (w_ == 2) ? 32768000ull : 34406400ull;
      r.x = fmaxf(fmaf(r.x, isf, shf) + rv.x, 0.f);
      r.y = fmaxf(fmaf(r.y, isf, shf) + rv.y, 0.f);
      r.z = fmaxf(fmaf(r.z, isf, shf) + rv.z, 0.f);
      r.w = fmaxf(fmaf(r.w, isf, shf) + rv.w, 0.f);
      *(float4*)(out + ob + idx) = r;
    }
  }
}

// ---------------------------------------------------------------------------
// W1 transpose (256x256) via LDS tiles, coalesced both sides. Run once/call.
// w1t[c'][c] = w1[c][c'] so mu_solve's W1@Y reads are coalesced.
// ---------------------------------------------------------------------------
__global__ __launch_bounds__(256)
void transpose_kernel(const float* __restrict__ w1, float* __restrict__ w1t)
{
  __shared__ float tile[32][33];
  const int bx = blockIdx.x, by = blockIdx.y;
  const int tx = threadIdx.x & 31, ty = threadIdx.x >> 5;  // 32 x 8
#pragma unroll
  for (int j = 0; j < 32; j += 8)
    tile[ty + j][tx] = w1[(size_t)(by * 32 + ty + j) * 256 + bx * 32 + tx];
  __syncthreads();
#pragma unroll
  for (int j = 0; j < 32; j += 8)
    w1t[(size_t)(bx * 32 + ty + j) * 256 + by * 32 + tx] = tile[tx][ty + j];
}

// ---------------------------------------------------------------------------
// t0: t0[c,k] = sum_c' W1[c',c]*mu0[c',k];  s0[k] = sum_c b1[c]*mu0[c,k].
// mu0 is batch-broadcast. block = k (64), threads = c (256).
// W1[c'*256+c]: threads c consecutive -> coalesced.
// ---------------------------------------------------------------------------
__global__ __launch_bounds__(256)
void t0_kernel(const float* __restrict__ w1, const float* __restrict__ b1,
               const float* __restrict__ mu0, float* __restrict__ t0,
               float* __restrict__ s0)
{
  const int k = blockIdx.x, c = threadIdx.x;
  __shared__ float M[256];
  __shared__ float red[256];
  M[c] = mu0[(size_t)c * 64 + k];
  __syncthreads();
  float acc = 0.f;
#pragma unroll 8
  for (int cp = 0; cp < 256; ++cp)
    acc = fmaf(w1[(size_t)cp * 256 + c], M[cp], acc);
  t0[(size_t)c * 64 + k] = acc;
  red[c] = b1[c] * M[c];
  __syncthreads();
  for (int off = 128; off > 0; off >>= 1) {
    if (c < off) red[c] += red[c + off];
    __syncthreads();
  }
  if (c == 0) s0[k] = red[0];
}

// ---------------------------------------------------------------------------
// z kernel: z[n,k] = softmax_k( sum_c X[c,n]*t[c,k] + s[k] ), X gathered from
// the 4 input scales (same gather pattern the old conv1 used).
// tile: 128 n x 64 k, 256 threads, thread = 8n x 4k; 16-lane shuffle softmax.
// ---------------------------------------------------------------------------
__global__ __launch_bounds__(256)
void z_kernel(const float* __restrict__ x0, const float* __restrict__ x1,
              const float* __restrict__ x2, const float* __restrict__ x3,
              const float* __restrict__ t, const float* __restrict__ s,
              int per_batch, float* __restrict__ zbuf)
{
  __shared__ float xs[32][136];  // [cc][n]
  __shared__ float mus[32][68];  // [cc][k]
  const int tid = threadIdx.x;
  const int n0 = blockIdx.x * 128;
  const int b  = blockIdx.y;
  const float* tb = t + (per_batch ? (size_t)b * 256 * 64 : 0);
  const float* sb = s + (per_batch ? (size_t)b * 64 : 0);
  const int tk = tid & 15, tn = tid >> 4;
  const float4 sv = *(const float4*)(sb + tk * 4);

  float acc[8][4];
#pragma unroll
  for (int r = 0; r < 8; ++r)
#pragma unroll
    for (int j = 0; j < 4; ++j) acc[r][j] = 0.f;

  for (int c0 = 0; c0 < 256; c0 += 32) {
#pragma unroll
    for (int it = 0; it < 4; ++it) {
      const int cc  = (tid >> 5) + 8 * it;
      const int nn4 = (tid & 31) * 4;
      const int gn  = n0 + nn4;
      float4 v = make_float4(0.f, 0.f, 0.f, 0.f);
      if (gn < NTOT) {
        int w_; size_t idx = in_index(gn, b * 256 + c0 + cc, &w_);
        const float* src = (w_ == 0) ? x0 : (w_ == 1) ? x1 : (w_ == 2) ? x2 : x3;
        v = *(const float4*)(src + idx);
      }
      *(float4*)&xs[cc][nn4] = v;
    }
#pragma unroll
    for (int it = 0; it < 2; ++it) {
      const int cc  = (tid >> 4) + 16 * it;
      const int kk4 = (tid & 15) * 4;
      float4 v = *(const float4*)(tb + (size_t)(c0 + cc) * 64 + kk4);
      *(float4*)&mus[cc][kk4] = v;
    }
    __syncthreads();
#pragma unroll
    for (int cc = 0; cc < 32; ++cc) {
      float4 m4 = *(const float4*)&mus[cc][tk * 4];
      float4 xa = *(const float4*)&xs[cc][tn * 8];
      float4 xb = *(const float4*)&xs[cc][tn * 8 + 4];
      float xv[8] = {xa.x, xa.y, xa.z, xa.w, xb.x, xb.y, xb.z, xb.w};
      float mv[4] = {m4.x, m4.y, m4.z, m4.w};
#pragma unroll
      for (int r = 0; r < 8; ++r)
#pragma unroll
        for (int j = 0; j < 4; ++j)
          acc[r][j] = fmaf(xv[r], mv[j], acc[r][j]);
    }
    __syncthreads();
  }

#pragma unroll
  for (int r = 0; r < 8; ++r) {
    acc[r][0] += sv.x; acc[r][1] += sv.y; acc[r][2] += sv.z; acc[r][3] += sv.w;
    float mx = fmaxf(fmaxf(acc[r][0], acc[r][1]), fmaxf(acc[r][2], acc[r][3]));
#pragma unroll
    for (int off = 8; off >= 1; off >>= 1) mx = fmaxf(mx, __shfl_xor(mx, off));
    float e0 = __expf(acc[r][0] - mx), e1 = __expf(acc[r][1] - mx);
    float e2 = __expf(acc[r][2] - mx), e3 = __expf(acc[r][3] - mx);
    float ssum = e0 + e1 + e2 + e3;
#pragma unroll
    for (int off = 8; off >= 1; off >>= 1) ssum += __shfl_xor(ssum, off);
    const float inv = 1.0f / ssum;
    const int gn = n0 + tn * 8 + r;
    if (gn < NTOT) {
      float4 w = make_float4(e0 * inv, e1 * inv, e2 * inv, e3 * inv);
      *(float4*)(zbuf + ((size_t)b * NTOT + gn) * 64 + tk * 4) = w;
    }
  }
}

// ---------------------------------------------------------------------------
// mu partial: part[b,ch,k,c] = sum_{n in chunk} X[c,n]*z[n,k]  (X gathered)
// plus colsum partials csum[b,ch,k] = sum_{n in chunk} z[n,k] (y==0 blocks).
// tile: 128 c x 64 k, 256 threads, thread = 8c x 4k, chunk = 512 n
// ---------------------------------------------------------------------------
__global__ __launch_bounds__(256)
void mu_part_kernel(const float* __restrict__ x0, const float* __restrict__ x1,
                    const float* __restrict__ x2, const float* __restrict__ x3,
                    const float* __restrict__ z, float* __restrict__ part,
                    float* __restrict__ csum)
{
  __shared__ float As[32][132];  // [nn][c]
  __shared__ float Bs[32][68];   // [nn][k]
  const int t  = threadIdx.x;
  const int ch = blockIdx.x;         // 0..16
  const int c0 = blockIdx.y * 128;   // 0,128
  const int b  = blockIdx.z;
  const int nb = ch * 512;
  const int tk = t & 15, tc = t >> 4;
  const bool do_cs = (blockIdx.y == 0);

  float acc[8][4];
#pragma unroll
  for (int i = 0; i < 8; ++i)
#pragma unroll
    for (int j = 0; j < 4; ++j) acc[i][j] = 0.f;
  float cs[4] = {0.f, 0.f, 0.f, 0.f};

  for (int kb = 0; kb < 512; kb += 32) {
#pragma unroll
    for (int it = 0; it < 4; ++it) {
      const int c_l = (t >> 3) + 32 * it;
      const int nn4 = (t & 7) * 4;
      const int gn  = nb + kb + nn4;
      float4 v = make_float4(0.f, 0.f, 0.f, 0.f);
      if (gn < NTOT) {
        int w_; size_t idx = in_index(gn, b * 256 + c0 + c_l, &w_);
        const float* src = (w_ == 0) ? x0 : (w_ == 1) ? x1 : (w_ == 2) ? x2 : x3;
        v = *(const float4*)(src + idx);
      }
      As[nn4 + 0][c_l] = v.x; As[nn4 + 1][c_l] = v.y;
      As[nn4 + 2][c_l] = v.z; As[nn4 + 3][c_l] = v.w;
    }
#pragma unroll
    for (int it = 0; it < 2; ++it) {
      const int nn  = (t >> 4) + 16 * it;
      const int kk4 = (t & 15) * 4;
      const int gn  = nb + kb + nn;
      float4 v = (gn < NTOT)
          ? *(const float4*)(z + ((size_t)b * NTOT + gn) * 64 + kk4)
          : make_float4(0.f, 0.f, 0.f, 0.f);
      *(float4*)&Bs[nn][kk4] = v;
    }
    __syncthreads();
    if (do_cs && tc == 0) {
#pragma unroll
      for (int nn = 0; nn < 32; ++nn) {
#pragma unroll
        for (int j = 0; j < 4; ++j) cs[j] += Bs[nn][tk * 4 + j];
      }
    }
#pragma unroll
    for (int nn = 0; nn < 32; ++nn) {
      float4 a0 = *(const float4*)&As[nn][tc * 8];
      float4 a1 = *(const float4*)&As[nn][tc * 8 + 4];
      float4 bz = *(const float4*)&Bs[nn][tk * 4];
      float av[8] = {a0.x, a0.y, a0.z, a0.w, a1.x, a1.y, a1.z, a1.w};
      float bv[4] = {bz.x, bz.y, bz.z, bz.w};
#pragma unroll
      for (int i = 0; i < 8; ++i)
#pragma unroll
        for (int j = 0; j < 4; ++j)
          acc[i][j] = fmaf(av[i], bv[j], acc[i][j]);
    }
    __syncthreads();
  }

#pragma unroll
  for (int j = 0; j < 4; ++j) {
    const int k = tk * 4 + j;
    float4 v0 = make_float4(acc[0][j], acc[1][j], acc[2][j], acc[3][j]);
    float4 v1 = make_float4(acc[4][j], acc[5][j], acc[6][j], acc[7][j]);
    size_t base = (((size_t)b * 17 + ch) * 64 + k) * 256 + c0 + tc * 8;
    *(float4*)(part + base)     = v0;
    *(float4*)(part + base + 4) = v1;
  }
  if (do_cs && tc == 0) {
#pragma unroll
    for (int j = 0; j < 4; ++j)
      csum[((size_t)b * 17 + ch) * 64 + tk * 4 + j] = cs[j];
  }
}

// ---------------------------------------------------------------------------
// mu solve: Y[c] = sum_ch part;  mu[:,k] = l2norm(W1@Y + b1*colsum);
// then next-stage t[c,k] = sum_c' W1[c',c]*mu[c',k], s[k] = b1 . mu[:,k].
// block = (k 64, b 16), threads = c (256). W1T used so W1@Y is coalesced.
// ---------------------------------------------------------------------------
__global__ __launch_bounds__(256)
void mu_solve_kernel(const float* __restrict__ part, const float* __restrict__ csum,
                     const float* __restrict__ w1t, const float* __restrict__ w1,
                     const float* __restrict__ b1,
                     float* __restrict__ muws, float* __restrict__ tbuf,
                     float* __restrict__ sbuf, float* __restrict__ mu_out)
{
  const int k = blockIdx.x, b = blockIdx.y, c = threadIdx.x;
  __shared__ float Y[256];
  __shared__ float M[256];
  __shared__ float red[256];

  float y = 0.f;
  for (int ch = 0; ch < 17; ++ch)
    y += part[(((size_t)b * 17 + ch) * 64 + k) * 256 + c];
  Y[c] = y;
  float csv = 0.f;
  for (int ch = 0; ch < 17; ++ch)
    csv += csum[((size_t)b * 17 + ch) * 64 + k];
  __syncthreads();

  float acc = 0.f;
#pragma unroll 8
  for (int cp = 0; cp < 256; ++cp)
    acc = fmaf(w1t[(size_t)cp * 256 + c], Y[cp], acc);
  acc = fmaf(b1[c], csv, acc);

  red[c] = acc * acc;
  __syncthreads();
  for (int off = 128; off > 0; off >>= 1) {
    if (c < off) red[c] += red[c + off];
    __syncthreads();
  }
  const float val = acc / (1e-6f + sqrtf(red[0]));
  M[c] = val;
  muws[((size_t)b * 256 + c) * 64 + k] = val;
  if (mu_out) mu_out[((size_t)b * 256 + c) * 64 + k] = val;
  __syncthreads();

  float acc2 = 0.f;
#pragma unroll 8
  for (int cp = 0; cp < 256; ++cp)
    acc2 = fmaf(w1[(size_t)cp * 256 + c], M[cp], acc2);
  tbuf[((size_t)b * 256 + c) * 64 + k] = acc2;

  red[c] = b1[c] * val;
  __syncthreads();
  for (int off = 128; off > 0; off >>= 1) {
    if (c < off) red[c] += red[c + off];
    __syncthreads();
  }
  if (c == 0) sbuf[(size_t)b * 64 + k] = red[0];
}

// ---------------------------------------------------------------------------
// rec kernel: x_rec[c,n] = relu( sum_k mu[c,k]*z[n,k] ), K-chunks of 16
// (bounded-liveness structure from round 3; VGPR ~52, no spills).
// ---------------------------------------------------------------------------
__global__ __launch_bounds__(256)
void rec_kernel(const float* __restrict__ mu, const float* __restrict__ z,
                float* __restrict__ xrec)
{
  __shared__ float As[16][68];    // [kk][c]
  __shared__ float Bs[16][132];   // [kk][n]
  const int t  = threadIdx.x;
  const int n0 = blockIdx.x * 128;
  const int c0 = blockIdx.y * 64;
  const int b  = blockIdx.z;
  const int tm = t & 15, tn = t >> 4;

  float acc[4][8];
#pragma unroll
  for (int i = 0; i < 4; ++i)
#pragma unroll
    for (int j = 0; j < 8; ++j) acc[i][j] = 0.f;

  for (int k0 = 0; k0 < 64; k0 += 16) {
    {
      const int c_l = t >> 2;
      const int kk4 = (t & 3) * 4;
      float4 v = *(const float4*)(mu + ((size_t)(b * 256 + c0 + c_l)) * 64 + k0 + kk4);
      As[kk4 + 0][c_l] = v.x; As[kk4 + 1][c_l] = v.y;
      As[kk4 + 2][c_l] = v.z; As[kk4 + 3][c_l] = v.w;
    }
#pragma unroll
    for (int it = 0; it < 2; ++it) {
      const int nn  = (t >> 2) + 64 * it;
      const int kk4 = (t & 3) * 4;
      const int gn  = n0 + nn;
      float4 v = (gn < NTOT)
          ? *(const float4*)(z + ((size_t)b * NTOT + gn) * 64 + k0 + kk4)
          : make_float4(0.f, 0.f, 0.f, 0.f);
      Bs[kk4 + 0][nn] = v.x; Bs[kk4 + 1][nn] = v.y;
      Bs[kk4 + 2][nn] = v.z; Bs[kk4 + 3][nn] = v.w;
    }
    __syncthreads();
#pragma unroll
    for (int kk = 0; kk < 16; ++kk) {
      float4 a = *(const float4*)&As[kk][tm * 4];
      float4 p = *(const float4*)&Bs[kk][tn * 8];
      float4 q = *(const float4*)&Bs[kk][tn * 8 + 4];
      float av[4] = {a.x, a.y, a.z, a.w};
      float bv[8] = {p.x, p.y, p.z, p.w, q.x, q.y, q.z, q.w};
#pragma unroll
      for (int i = 0; i < 4; ++i)
#pragma unroll
        for (int j = 0; j < 8; ++j)
          acc[i][j] = fmaf(av[i], bv[j], acc[i][j]);
    }
    __syncthreads();
  }

#pragma unroll
  for (int i = 0; i < 4; ++i) {
    const int cc = c0 + tm * 4 + i;
#pragma unroll
    for (int jj = 0; jj < 8; jj += 4) {
      const int gn = n0 + tn * 8 + jj;
      if (gn >= NTOT) continue;
      float4 r = make_float4(fmaxf(acc[i][jj + 0], 0.f), fmaxf(acc[i][jj + 1], 0.f),
                             fmaxf(acc[i][jj + 2], 0.f), fmaxf(acc[i][jj + 3], 0.f));
      *(float4*)(xrec + (size_t)(b * 256 + cc) * NTOT + gn) = r;
    }
  }
}

// ---------------------------------------------------------------------------
extern "C" void kernel_launch(void* const* d_in, const int* in_sizes, int n_in,
                              void* d_out, int out_size, void* d_ws, size_t ws_size,
                              hipStream_t stream)
{
  const float* x0   = (const float*)d_in[0];
  const float* x1   = (const float*)d_in[1];
  const float* x2   = (const float*)d_in[2];
  const float* x3   = (const float*)d_in[3];
  const float* w1   = (const float*)d_in[4];
  const float* b1   = (const float*)d_in[5];
  const float* w2   = (const float*)d_in[6];
  const float* bn_g = (const float*)d_in[7];
  const float* bn_b = (const float*)d_in[8];
  const float* bn_m = (const float*)d_in[9];
  const float* bn_v = (const float*)d_in[10];
  const float* mu0  = (const float*)d_in[11];
  float* out = (float*)d_out;

  float* xr   = (float*)d_ws;              // 16*256*8500   = 34,816,000 f
  float* z    = xr   + 34816000ull;        // 16*8500*64    =  8,704,000 f
  float* part = z    + 8704000ull;         // 16*17*64*256  =  4,456,448 f
  float* muws = part + 4456448ull;         // 16*256*64     =    262,144 f
  float* tbuf = muws + 262144ull;          // 16*256*64     =    262,144 f
  float* sbuf = tbuf + 262144ull;          // 16*64         =      1,024 f
  float* t0b  = sbuf + 1024ull;            // 256*64        =     16,384 f
  float* s0b  = t0b  + 16384ull;           // 64            =         64 f
  float* csum = s0b  + 64ull;              // 16*17*64      =     17,408 f
  float* w1t  = csum + 17408ull;           // 256*256       =     65,536 f

  transpose_kernel<<<dim3(8, 8), 256, 0, stream>>>(w1, w1t);
  t0_kernel<<<64, 256, 0, stream>>>(w1, b1, mu0, t0b, s0b);

  for (int s = 0; s < 3; ++s) {
    z_kernel<<<dim3(67, 16), 256, 0, stream>>>(
        x0, x1, x2, x3, s == 0 ? t0b : tbuf, s == 0 ? s0b : sbuf,
        s == 0 ? 0 : 1, z);
    mu_part_kernel<<<dim3(17, 2, 16), 256, 0, stream>>>(
        x0, x1, x2, x3, z, part, csum);
    mu_solve_kernel<<<dim3(64, 16), 256, 0, stream>>>(
        part, csum, w1t, w1, b1, muws, tbuf, sbuf,
        (s == 2) ? (out + 34816000ull) : nullptr);
  }
  rec_kernel<<<dim3(67, 4, 16), 256, 0, stream>>>(muws, z, xr);
  conv2_kernel<<<dim3(67, 4, 16), 256, 0, stream>>>(
      w2, x0, x1, x2, x3, xr, bn_g, bn_b, bn_m, bn_v, out);
}

// Round 8
// 1137.389 us; speedup vs baseline: 1.1501x; 1.1501x over previous
//
#include <hip/hip_runtime.h>
#include <math.h>

#define NTOT 8500

// ---------------------------------------------------------------------------
// Geometry: 4 scales concatenated along n: [6400 | 1600 | 400 | 100] = 8500.
// All boundaries divisible by 4 -> float4 loads never straddle scales.
//
// Structure (round 8): conv1 GEMM is algebraically eliminated:
//   z-logits = X^T (W1^T mu) + (b1 . mu_k)
//   mu'      = l2norm( W1 (X z) + b1 * colsum(z) )
// X is gathered ONCE into contiguous xcat (pure copy, ~55us) so the 6 big
// EM GEMM passes read contiguous memory (round-7 lesson: per-pass gather
// in the staging loops cost ~350us of VALU).
// ---------------------------------------------------------------------------
__device__ __forceinline__ size_t in_index(int gn, int bc, int* which) {
  if (gn < 6400) { *which = 0; return (size_t)bc * 6400 + gn; }
  if (gn < 8000) { *which = 1; return (size_t)bc * 1600 + (gn - 6400); }
  if (gn < 8400) { *which = 2; return (size_t)bc * 400  + (gn - 8000); }
  *which = 3;     return (size_t)bc * 100  + (gn - 8400);
}

// ---------------------------------------------------------------------------
// concat: xcat[bc][gn] = X_scale(gn)[bc][local(gn)]  (pure gather-copy, once)
// ---------------------------------------------------------------------------
__global__ __launch_bounds__(256)
void concat_kernel(const float* __restrict__ x0, const float* __restrict__ x1,
                   const float* __restrict__ x2, const float* __restrict__ x3,
                   float* __restrict__ xcat)
{
  const int bc = blockIdx.y;                       // b*256 + c
  const int gn = (blockIdx.x * 256 + threadIdx.x) * 4;
  if (gn >= NTOT) return;
  int w_; size_t idx = in_index(gn, bc, &w_);
  const float* src = (w_ == 0) ? x0 : (w_ == 1) ? x1 : (w_ == 2) ? x2 : x3;
  *(float4*)(xcat + (size_t)bc * NTOT + gn) = *(const float4*)(src + idx);
}

// ---------------------------------------------------------------------------
// conv2: per batch GEMM out[o,n] = sum_c W[o,c]*xrec[c,n], epilogue BN +
// residual + relu, scattered writes into the 4 output scale segments.
// tile: 64 (o) x 128 (n), 256 threads, thread = 4x8, K-chunks of 32.
// ---------------------------------------------------------------------------
__global__ __launch_bounds__(256)
void conv2_kernel(const float* __restrict__ W,
                  const float* __restrict__ x0, const float* __restrict__ x1,
                  const float* __restrict__ x2, const float* __restrict__ x3,
                  const float* __restrict__ xrec,
                  const float* __restrict__ bn_g, const float* __restrict__ bn_b,
                  const float* __restrict__ bn_m, const float* __restrict__ bn_v,
                  float* __restrict__ out)
{
  __shared__ float As[32][68];    // [kk][o]
  __shared__ float Bs[32][132];   // [kk][n]
  const int t  = threadIdx.x;
  const int n0 = blockIdx.x * 128;
  const int m0 = blockIdx.y * 64;
  const int b  = blockIdx.z;
  const int tm = t & 15, tn = t >> 4;

  float acc[4][8];
#pragma unroll
  for (int i = 0; i < 4; ++i)
#pragma unroll
    for (int j = 0; j < 8; ++j) acc[i][j] = 0.f;

  for (int k0 = 0; k0 < 256; k0 += 32) {
#pragma unroll
    for (int it = 0; it < 2; ++it) {
      const int o_l = (t >> 3) + 32 * it;
      const int kk4 = (t & 7) * 4;
      float4 v = *(const float4*)(W + (size_t)(m0 + o_l) * 256 + k0 + kk4);
      As[kk4 + 0][o_l] = v.x; As[kk4 + 1][o_l] = v.y;
      As[kk4 + 2][o_l] = v.z; As[kk4 + 3][o_l] = v.w;
    }
#pragma unroll
    for (int it = 0; it < 4; ++it) {
      const int kk  = (t >> 5) + 8 * it;
      const int nn4 = (t & 31) * 4;
      const int gn  = n0 + nn4;
      float4 v = make_float4(0.f, 0.f, 0.f, 0.f);
      if (gn < NTOT)
        v = *(const float4*)(xrec + (size_t)(b * 256 + k0 + kk) * NTOT + gn);
      *(float4*)&Bs[kk][nn4] = v;
    }
    __syncthreads();
#pragma unroll
    for (int kk = 0; kk < 32; ++kk) {
      float4 a = *(const float4*)&As[kk][tm * 4];
      float4 p = *(const float4*)&Bs[kk][tn * 8];
      float4 q = *(const float4*)&Bs[kk][tn * 8 + 4];
      float av[4] = {a.x, a.y, a.z, a.w};
      float bv[8] = {p.x, p.y, p.z, p.w, q.x, q.y, q.z, q.w};
#pragma unroll
      for (int i = 0; i < 4; ++i)
#pragma unroll
        for (int j = 0; j < 8; ++j)
          acc[i][j] = fmaf(av[i], bv[j], acc[i][j]);
    }
    __syncthreads();
  }

#pragma unroll
  for (int i = 0; i < 4; ++i) {
    const int o = m0 + tm * 4 + i;
    float g   = bn_g[o];
    float isf = g / sqrtf(bn_v[o] + 1e-5f);
    float shf = bn_b[o] - bn_m[o] * isf;
#pragma unroll
    for (int jj = 0; jj < 8; jj += 4) {
      const int gn = n0 + tn * 8 + jj;
      if (gn >= NTOT) continue;
      float4 r = make_float4(acc[i][jj + 0], acc[i][jj + 1],
                             acc[i][jj + 2], acc[i][jj + 3]);
      int w_; size_t idx = in_index(gn, b * 256 + o, &w_);
      const float* src = (w_ == 0) ? x0 : (w_ == 1) ? x1 : (w_ == 2) ? x2 : x3;
      float4 rv = *(const float4*)(src + idx);
      size_t ob = (w_ == 0) ? 0ull : (w_ == 1) ? 26214400ull
                : (w_ == 2) ? 32768000ull : 34406400ull;
      r.x = fmaxf(fmaf(r.x, isf, shf) + rv.x, 0.f);
      r.y = fmaxf(fmaf(r.y, isf, shf) + rv.y, 0.f);
      r.z = fmaxf(fmaf(r.z, isf, shf) + rv.z, 0.f);
      r.w = fmaxf(fmaf(r.w, isf, shf) + rv.w, 0.f);
      *(float4*)(out + ob + idx) = r;
    }
  }
}

// ---------------------------------------------------------------------------
// W1 transpose (256x256) via LDS tiles, coalesced both sides. Run once/call.
// ---------------------------------------------------------------------------
__global__ __launch_bounds__(256)
void transpose_kernel(const float* __restrict__ w1, float* __restrict__ w1t)
{
  __shared__ float tile[32][33];
  const int bx = blockIdx.x, by = blockIdx.y;
  const int tx = threadIdx.x & 31, ty = threadIdx.x >> 5;  // 32 x 8
#pragma unroll
  for (int j = 0; j < 32; j += 8)
    tile[ty + j][tx] = w1[(size_t)(by * 32 + ty + j) * 256 + bx * 32 + tx];
  __syncthreads();
#pragma unroll
  for (int j = 0; j < 32; j += 8)
    w1t[(size_t)(bx * 32 + ty + j) * 256 + by * 32 + tx] = tile[tx][ty + j];
}

// ---------------------------------------------------------------------------
// t0: t0[c,k] = sum_c' W1[c',c]*mu0[c',k];  s0[k] = sum_c b1[c]*mu0[c,k].
// ---------------------------------------------------------------------------
__global__ __launch_bounds__(256)
void t0_kernel(const float* __restrict__ w1, const float* __restrict__ b1,
               const float* __restrict__ mu0, float* __restrict__ t0,
               float* __restrict__ s0)
{
  const int k = blockIdx.x, c = threadIdx.x;
  __shared__ float M[256];
  __shared__ float red[256];
  M[c] = mu0[(size_t)c * 64 + k];
  __syncthreads();
  float acc = 0.f;
#pragma unroll 8
  for (int cp = 0; cp < 256; ++cp)
    acc = fmaf(w1[(size_t)cp * 256 + c], M[cp], acc);
  t0[(size_t)c * 64 + k] = acc;
  red[c] = b1[c] * M[c];
  __syncthreads();
  for (int off = 128; off > 0; off >>= 1) {
    if (c < off) red[c] += red[c + off];
    __syncthreads();
  }
  if (c == 0) s0[k] = red[0];
}

// ---------------------------------------------------------------------------
// z kernel: z[n,k] = softmax_k( sum_c xcat[c,n]*t[c,k] + s[k] )
// tile: 128 n x 64 k, 256 threads, thread = 8n x 4k; 16-lane shuffle softmax.
// ---------------------------------------------------------------------------
__global__ __launch_bounds__(256)
void z_kernel(const float* __restrict__ xcat,
              const float* __restrict__ t, const float* __restrict__ s,
              int per_batch, float* __restrict__ zbuf)
{
  __shared__ float xs[32][136];  // [cc][n]
  __shared__ float mus[32][68];  // [cc][k]
  const int tid = threadIdx.x;
  const int n0 = blockIdx.x * 128;
  const int b  = blockIdx.y;
  const float* tb = t + (per_batch ? (size_t)b * 256 * 64 : 0);
  const float* sb = s + (per_batch ? (size_t)b * 64 : 0);
  const int tk = tid & 15, tn = tid >> 4;
  const float4 sv = *(const float4*)(sb + tk * 4);

  float acc[8][4];
#pragma unroll
  for (int r = 0; r < 8; ++r)
#pragma unroll
    for (int j = 0; j < 4; ++j) acc[r][j] = 0.f;

  for (int c0 = 0; c0 < 256; c0 += 32) {
#pragma unroll
    for (int it = 0; it < 4; ++it) {
      const int cc  = (tid >> 5) + 8 * it;
      const int nn4 = (tid & 31) * 4;
      const int gn  = n0 + nn4;
      float4 v = (gn < NTOT)
          ? *(const float4*)(xcat + (size_t)(b * 256 + c0 + cc) * NTOT + gn)
          : make_float4(0.f, 0.f, 0.f, 0.f);
      *(float4*)&xs[cc][nn4] = v;
    }
#pragma unroll
    for (int it = 0; it < 2; ++it) {
      const int cc  = (tid >> 4) + 16 * it;
      const int kk4 = (tid & 15) * 4;
      float4 v = *(const float4*)(tb + (size_t)(c0 + cc) * 64 + kk4);
      *(float4*)&mus[cc][kk4] = v;
    }
    __syncthreads();
#pragma unroll
    for (int cc = 0; cc < 32; ++cc) {
      float4 m4 = *(const float4*)&mus[cc][tk * 4];
      float4 xa = *(const float4*)&xs[cc][tn * 8];
      float4 xb = *(const float4*)&xs[cc][tn * 8 + 4];
      float xv[8] = {xa.x, xa.y, xa.z, xa.w, xb.x, xb.y, xb.z, xb.w};
      float mv[4] = {m4.x, m4.y, m4.z, m4.w};
#pragma unroll
      for (int r = 0; r < 8; ++r)
#pragma unroll
        for (int j = 0; j < 4; ++j)
          acc[r][j] = fmaf(xv[r], mv[j], acc[r][j]);
    }
    __syncthreads();
  }

#pragma unroll
  for (int r = 0; r < 8; ++r) {
    acc[r][0] += sv.x; acc[r][1] += sv.y; acc[r][2] += sv.z; acc[r][3] += sv.w;
    float mx = fmaxf(fmaxf(acc[r][0], acc[r][1]), fmaxf(acc[r][2], acc[r][3]));
#pragma unroll
    for (int off = 8; off >= 1; off >>= 1) mx = fmaxf(mx, __shfl_xor(mx, off));
    float e0 = __expf(acc[r][0] - mx), e1 = __expf(acc[r][1] - mx);
    float e2 = __expf(acc[r][2] - mx), e3 = __expf(acc[r][3] - mx);
    float ssum = e0 + e1 + e2 + e3;
#pragma unroll
    for (int off = 8; off >= 1; off >>= 1) ssum += __shfl_xor(ssum, off);
    const float inv = 1.0f / ssum;
    const int gn = n0 + tn * 8 + r;
    if (gn < NTOT) {
      float4 w = make_float4(e0 * inv, e1 * inv, e2 * inv, e3 * inv);
      *(float4*)(zbuf + ((size_t)b * NTOT + gn) * 64 + tk * 4) = w;
    }
  }
}

// ---------------------------------------------------------------------------
// mu partial: part[b,ch,k,c] = sum_{n in chunk} xcat[c,n]*z[n,k]
// plus colsum partials csum[b,ch,k] = sum_{n in chunk} z[n,k] (y==0 blocks).
// tile: 128 c x 64 k, 256 threads, thread = 8c x 4k, chunk = 512 n
// ---------------------------------------------------------------------------
__global__ __launch_bounds__(256)
void mu_part_kernel(const float* __restrict__ xcat,
                    const float* __restrict__ z, float* __restrict__ part,
                    float* __restrict__ csum)
{
  __shared__ float As[32][132];  // [nn][c]
  __shared__ float Bs[32][68];   // [nn][k]
  const int t  = threadIdx.x;
  const int ch = blockIdx.x;         // 0..16
  const int c0 = blockIdx.y * 128;   // 0,128
  const int b  = blockIdx.z;
  const int nb = ch * 512;
  const int tk = t & 15, tc = t >> 4;
  const bool do_cs = (blockIdx.y == 0);

  float acc[8][4];
#pragma unroll
  for (int i = 0; i < 8; ++i)
#pragma unroll
    for (int j = 0; j < 4; ++j) acc[i][j] = 0.f;
  float cs[4] = {0.f, 0.f, 0.f, 0.f};

  for (int kb = 0; kb < 512; kb += 32) {
#pragma unroll
    for (int it = 0; it < 4; ++it) {
      const int c_l = (t >> 3) + 32 * it;
      const int nn4 = (t & 7) * 4;
      const int gn  = nb + kb + nn4;
      float4 v = (gn < NTOT)
          ? *(const float4*)(xcat + (size_t)(b * 256 + c0 + c_l) * NTOT + gn)
          : make_float4(0.f, 0.f, 0.f, 0.f);
      As[nn4 + 0][c_l] = v.x; As[nn4 + 1][c_l] = v.y;
      As[nn4 + 2][c_l] = v.z; As[nn4 + 3][c_l] = v.w;
    }
#pragma unroll
    for (int it = 0; it < 2; ++it) {
      const int nn  = (t >> 4) + 16 * it;
      const int kk4 = (t & 15) * 4;
      const int gn  = nb + kb + nn;
      float4 v = (gn < NTOT)
          ? *(const float4*)(z + ((size_t)b * NTOT + gn) * 64 + kk4)
          : make_float4(0.f, 0.f, 0.f, 0.f);
      *(float4*)&Bs[nn][kk4] = v;
    }
    __syncthreads();
    if (do_cs && tc == 0) {
#pragma unroll
      for (int nn = 0; nn < 32; ++nn) {
#pragma unroll
        for (int j = 0; j < 4; ++j) cs[j] += Bs[nn][tk * 4 + j];
      }
    }
#pragma unroll
    for (int nn = 0; nn < 32; ++nn) {
      float4 a0 = *(const float4*)&As[nn][tc * 8];
      float4 a1 = *(const float4*)&As[nn][tc * 8 + 4];
      float4 bz = *(const float4*)&Bs[nn][tk * 4];
      float av[8] = {a0.x, a0.y, a0.z, a0.w, a1.x, a1.y, a1.z, a1.w};
      float bv[4] = {bz.x, bz.y, bz.z, bz.w};
#pragma unroll
      for (int i = 0; i < 8; ++i)
#pragma unroll
        for (int j = 0; j < 4; ++j)
          acc[i][j] = fmaf(av[i], bv[j], acc[i][j]);
    }
    __syncthreads();
  }

#pragma unroll
  for (int j = 0; j < 4; ++j) {
    const int k = tk * 4 + j;
    float4 v0 = make_float4(acc[0][j], acc[1][j], acc[2][j], acc[3][j]);
    float4 v1 = make_float4(acc[4][j], acc[5][j], acc[6][j], acc[7][j]);
    size_t base = (((size_t)b * 17 + ch) * 64 + k) * 256 + c0 + tc * 8;
    *(float4*)(part + base)     = v0;
    *(float4*)(part + base + 4) = v1;
  }
  if (do_cs && tc == 0) {
#pragma unroll
    for (int j = 0; j < 4; ++j)
      csum[((size_t)b * 17 + ch) * 64 + tk * 4 + j] = cs[j];
  }
}

// ---------------------------------------------------------------------------
// mu solve: Y[c] = sum_ch part;  mu[:,k] = l2norm(W1@Y + b1*colsum);
// then next-stage t[c,k] = sum_c' W1[c',c]*mu[c',k], s[k] = b1 . mu[:,k].
// ---------------------------------------------------------------------------
__global__ __launch_bounds__(256)
void mu_solve_kernel(const float* __restrict__ part, const float* __restrict__ csum,
                     const float* __restrict__ w1t, const float* __restrict__ w1,
                     const float* __restrict__ b1,
                     float* __restrict__ muws, float* __restrict__ tbuf,
                     float* __restrict__ sbuf, float* __restrict__ mu_out)
{
  const int k = blockIdx.x, b = blockIdx.y, c = threadIdx.x;
  __shared__ float Y[256];
  __shared__ float M[256];
  __shared__ float red[256];

  float y = 0.f;
  for (int ch = 0; ch < 17; ++ch)
    y += part[(((size_t)b * 17 + ch) * 64 + k) * 256 + c];
  Y[c] = y;
  float csv = 0.f;
  for (int ch = 0; ch < 17; ++ch)
    csv += csum[((size_t)b * 17 + ch) * 64 + k];
  __syncthreads();

  float acc = 0.f;
#pragma unroll 8
  for (int cp = 0; cp < 256; ++cp)
    acc = fmaf(w1t[(size_t)cp * 256 + c], Y[cp], acc);
  acc = fmaf(b1[c], csv, acc);

  red[c] = acc * acc;
  __syncthreads();
  for (int off = 128; off > 0; off >>= 1) {
    if (c < off) red[c] += red[c + off];
    __syncthreads();
  }
  const float val = acc / (1e-6f + sqrtf(red[0]));
  M[c] = val;
  muws[((size_t)b * 256 + c) * 64 + k] = val;
  if (mu_out) mu_out[((size_t)b * 256 + c) * 64 + k] = val;
  __syncthreads();

  float acc2 = 0.f;
#pragma unroll 8
  for (int cp = 0; cp < 256; ++cp)
    acc2 = fmaf(w1[(size_t)cp * 256 + c], M[cp], acc2);
  tbuf[((size_t)b * 256 + c) * 64 + k] = acc2;

  red[c] = b1[c] * val;
  __syncthreads();
  for (int off = 128; off > 0; off >>= 1) {
    if (c < off) red[c] += red[c + off];
    __syncthreads();
  }
  if (c == 0) sbuf[(size_t)b * 64 + k] = red[0];
}

// ---------------------------------------------------------------------------
// rec kernel: x_rec[c,n] = relu( sum_k mu[c,k]*z[n,k] ), K-chunks of 16
// (bounded-liveness structure; VGPR ~52, no spills). Writes into xcat.
// ---------------------------------------------------------------------------
__global__ __launch_bounds__(256)
void rec_kernel(const float* __restrict__ mu, const float* __restrict__ z,
                float* __restrict__ xrec)
{
  __shared__ float As[16][68];    // [kk][c]
  __shared__ float Bs[16][132];   // [kk][n]
  const int t  = threadIdx.x;
  const int n0 = blockIdx.x * 128;
  const int c0 = blockIdx.y * 64;
  const int b  = blockIdx.z;
  const int tm = t & 15, tn = t >> 4;

  float acc[4][8];
#pragma unroll
  for (int i = 0; i < 4; ++i)
#pragma unroll
    for (int j = 0; j < 8; ++j) acc[i][j] = 0.f;

  for (int k0 = 0; k0 < 64; k0 += 16) {
    {
      const int c_l = t >> 2;
      const int kk4 = (t & 3) * 4;
      float4 v = *(const float4*)(mu + ((size_t)(b * 256 + c0 + c_l)) * 64 + k0 + kk4);
      As[kk4 + 0][c_l] = v.x; As[kk4 + 1][c_l] = v.y;
      As[kk4 + 2][c_l] = v.z; As[kk4 + 3][c_l] = v.w;
    }
#pragma unroll
    for (int it = 0; it < 2; ++it) {
      const int nn  = (t >> 2) + 64 * it;
      const int kk4 = (t & 3) * 4;
      const int gn  = n0 + nn;
      float4 v = (gn < NTOT)
          ? *(const float4*)(z + ((size_t)b * NTOT + gn) * 64 + k0 + kk4)
          : make_float4(0.f, 0.f, 0.f, 0.f);
      Bs[kk4 + 0][nn] = v.x; Bs[kk4 + 1][nn] = v.y;
      Bs[kk4 + 2][nn] = v.z; Bs[kk4 + 3][nn] = v.w;
    }
    __syncthreads();
#pragma unroll
    for (int kk = 0; kk < 16; ++kk) {
      float4 a = *(const float4*)&As[kk][tm * 4];
      float4 p = *(const float4*)&Bs[kk][tn * 8];
      float4 q = *(const float4*)&Bs[kk][tn * 8 + 4];
      float av[4] = {a.x, a.y, a.z, a.w};
      float bv[8] = {p.x, p.y, p.z, p.w, q.x, q.y, q.z, q.w};
#pragma unroll
      for (int i = 0; i < 4; ++i)
#pragma unroll
        for (int j = 0; j < 8; ++j)
          acc[i][j] = fmaf(av[i], bv[j], acc[i][j]);
    }
    __syncthreads();
  }

#pragma unroll
  for (int i = 0; i < 4; ++i) {
    const int cc = c0 + tm * 4 + i;
#pragma unroll
    for (int jj = 0; jj < 8; jj += 4) {
      const int gn = n0 + tn * 8 + jj;
      if (gn >= NTOT) continue;
      float4 r = make_float4(fmaxf(acc[i][jj + 0], 0.f), fmaxf(acc[i][jj + 1], 0.f),
                             fmaxf(acc[i][jj + 2], 0.f), fmaxf(acc[i][jj + 3], 0.f));
      *(float4*)(xrec + (size_t)(b * 256 + cc) * NTOT + gn) = r;
    }
  }
}

// ---------------------------------------------------------------------------
extern "C" void kernel_launch(void* const* d_in, const int* in_sizes, int n_in,
                              void* d_out, int out_size, void* d_ws, size_t ws_size,
                              hipStream_t stream)
{
  const float* x0   = (const float*)d_in[0];
  const float* x1   = (const float*)d_in[1];
  const float* x2   = (const float*)d_in[2];
  const float* x3   = (const float*)d_in[3];
  const float* w1   = (const float*)d_in[4];
  const float* b1   = (const float*)d_in[5];
  const float* w2   = (const float*)d_in[6];
  const float* bn_g = (const float*)d_in[7];
  const float* bn_b = (const float*)d_in[8];
  const float* bn_m = (const float*)d_in[9];
  const float* bn_v = (const float*)d_in[10];
  const float* mu0  = (const float*)d_in[11];
  float* out = (float*)d_out;

  float* xcat = (float*)d_ws;              // 16*256*8500   = 34,816,000 f
  float* z    = xcat + 34816000ull;        // 16*8500*64    =  8,704,000 f
  float* part = z    + 8704000ull;         // 16*17*64*256  =  4,456,448 f
  float* muws = part + 4456448ull;         // 16*256*64     =    262,144 f
  float* tbuf = muws + 262144ull;          // 16*256*64     =    262,144 f
  float* sbuf = tbuf + 262144ull;          // 16*64         =      1,024 f
  float* t0b  = sbuf + 1024ull;            // 256*64        =     16,384 f
  float* s0b  = t0b  + 16384ull;           // 64            =         64 f
  float* csum = s0b  + 64ull;              // 16*17*64      =     17,408 f
  float* w1t  = csum + 17408ull;           // 256*256       =     65,536 f

  concat_kernel<<<dim3(9, 4096), 256, 0, stream>>>(x0, x1, x2, x3, xcat);
  transpose_kernel<<<dim3(8, 8), 256, 0, stream>>>(w1, w1t);
  t0_kernel<<<64, 256, 0, stream>>>(w1, b1, mu0, t0b, s0b);

  for (int s = 0; s < 3; ++s) {
    z_kernel<<<dim3(67, 16), 256, 0, stream>>>(
        xcat, s == 0 ? t0b : tbuf, s == 0 ? s0b : sbuf, s == 0 ? 0 : 1, z);
    mu_part_kernel<<<dim3(17, 2, 16), 256, 0, stream>>>(
        xcat, z, part, csum);
    mu_solve_kernel<<<dim3(64, 16), 256, 0, stream>>>(
        part, csum, w1t, w1, b1, muws, tbuf, sbuf,
        (s == 2) ? (out + 34816000ull) : nullptr);
  }
  rec_kernel<<<dim3(67, 4, 16), 256, 0, stream>>>(muws, z, xcat);
  conv2_kernel<<<dim3(67, 4, 16), 256, 0, stream>>>(
      w2, x0, x1, x2, x3, xcat, bn_g, bn_b, bn_m, bn_v, out);
}